// Round 12
// baseline (300.316 us; speedup 1.0000x reference)
//
#include <hip/hip_runtime.h>
#include <hip/hip_bf16.h>
#include <cmath>
#include <algorithm>

#define IN_DIM  64
#define HID     128
#define OUT_DIM 32
#define SIG_NC  14
#define SIG_CL  9.5f

typedef short    v8s __attribute__((ext_vector_type(8)));
typedef float    v4f __attribute__((ext_vector_type(4)));
typedef unsigned v4u __attribute__((ext_vector_type(4)));

struct SigP { float k1; float c[SIG_NC]; };   // sigmoid(v) ~ 0.5 + u*P(s), s = k1*u^2 - 1

__device__ __forceinline__ unsigned pk2(float a, float b) {
    __hip_bfloat162 p = __float22bfloat162_rn(make_float2(a, b));
    return *(unsigned*)&p;
}

// ---- poly swish: 0 transcendentals, ~18 VALU/value ----
__device__ __forceinline__ float swish_p(float v, const SigP& P) {
    float u = fminf(fmaxf(v, -SIG_CL), SIG_CL);     // v_med3
    float z = u * u;
    float s = fmaf(z, P.k1, -1.0f);
    float g = P.c[SIG_NC - 1];
    #pragma unroll
    for (int k = SIG_NC - 2; k >= 0; --k) g = fmaf(g, s, P.c[k]);
    float sig = fmaf(u, g, 0.5f);
    return v * sig;
}
__device__ __forceinline__ v4f swish_p4(v4f v, const SigP& P) {
    v4f r;
    r[0] = swish_p(v[0], P); r[1] = swish_p(v[1], P);
    r[2] = swish_p(v[2], P); r[3] = swish_p(v[3], P);
    return r;
}

// ---- exact fallback: grouped-reciprocal swish (5 trans / 4 values) ----
__device__ __forceinline__ v4f swish4(v4f v) {
    float e0 = __expf(fminf(-v[0], 20.0f));
    float e1 = __expf(fminf(-v[1], 20.0f));
    float e2 = __expf(fminf(-v[2], 20.0f));
    float e3 = __expf(fminf(-v[3], 20.0f));
    float w0 = 1.0f + e0, w1 = 1.0f + e1, w2 = 1.0f + e2, w3 = 1.0f + e3;
    float w01 = w0 * w1, w23 = w2 * w3;
    float r   = __builtin_amdgcn_rcpf(w01 * w23);
    float r01 = r * w23, r23 = r * w01;
    v4f s;
    s[0] = v[0] * (w1 * r01);
    s[1] = v[1] * (w0 * r01);
    s[2] = v[2] * (w3 * r23);
    s[3] = v[3] * (w2 * r23);
    return s;
}

// one-time x fp32 -> bf16 (row-major [N][64])
__global__ __launch_bounds__(1024)
void cvt_x(const float* __restrict__ x, ushort* __restrict__ xb, int n8) {
    int i = blockIdx.x * blockDim.x + threadIdx.x;
    if (i < n8) {
        float4 f0 = *(const float4*)(x + (size_t)i * 8);
        float4 f1 = *(const float4*)(x + (size_t)i * 8 + 4);
        uint4 u;
        u.x = pk2(f0.x, f0.y); u.y = pk2(f0.z, f0.w);
        u.z = pk2(f1.x, f1.y); u.w = pk2(f1.z, f1.w);
        *(uint4*)(xb + (size_t)i * 8) = u;
    }
}

// Channel-permuted weight staging (register-local layer handoff), bias in LDS,
// opaque-z anti-LICM launder. R10 base structure (183us main kernel).
// POLY=0 fallback carries a 4KB LDS pad as a dispatch FINGERPRINT:
// LDS_Block_Size 88064 => gate failed; 83968 => poly ran.
template<int BF16X, int POLY>
__global__ __launch_bounds__(1024, 1)
void subnet_mlp(const float* __restrict__ x,  const ushort* __restrict__ xbf,
                const float* __restrict__ W1, const float* __restrict__ b1,
                const float* __restrict__ Wh, const float* __restrict__ bh,
                const float* __restrict__ Wo, const float* __restrict__ bo,
                float* __restrict__ out, int n_iters, SigP SP)
{
    __shared__ __align__(16) short sW1[8 * 16 * 64];       // 16 KB
    __shared__ __align__(16) short sWh[2 * 8 * 16 * 128];  // 64 KB
    __shared__ __align__(16) float sBias[512];             // 2 KB

    const int tid   = threadIdx.x;
    const int o     = blockIdx.x >> 3;
    const int slice = blockIdx.x & 7;

    if constexpr (!POLY) {                 // fallback fingerprint (4 KB LDS)
        __shared__ float fpad[1024];
        if (tid == 0) ((volatile float*)fpad)[0] = 0.f;
    }

    char* const cW1 = (char*)sW1;
    char* const cWh = (char*)sWh;
    char* const cB  = (char*)sBias;

    {   // W1 staging: 1024 tasks (T,R,kg)
        const int R = tid & 15, T = (tid >> 4) & 7, kg = tid >> 7;
        const int c = 32 * (T >> 1) + 8 * (R >> 2) + 4 * (T & 1) + (R & 3);
        const float* p = W1 + ((size_t)o * IN_DIM + kg * 8) * HID + c;
        union { v8s v; unsigned u[4]; } cv;
        #pragma unroll
        for (int j = 0; j < 4; ++j)
            cv.u[j] = pk2(p[(2 * j) * HID], p[(2 * j + 1) * HID]);
        *(v8s*)(cW1 + T * 2048 + R * 128 + ((kg * 16) ^ ((R & 7) << 4))) = cv.v;
    }
    #pragma unroll
    for (int r = 0; r < 4; ++r) {   // Wh staging: 4096 tasks
        const int t = tid + r * 1024;
        const int R = t & 15, T = (t >> 4) & 7, kg = (t >> 7) & 15, l = t >> 11;
        const int c = 32 * (T >> 1) + 8 * (R >> 2) + 4 * (T & 1) + (R & 3);
        const float* p = Wh + (((size_t)l * OUT_DIM + o) * HID + kg * 8) * HID + c;
        union { v8s v; unsigned u[4]; } cv;
        #pragma unroll
        for (int j = 0; j < 4; ++j)
            cv.u[j] = pk2(p[(2 * j) * HID], p[(2 * j + 1) * HID]);
        *(v8s*)(cWh + l * 32768 + T * 4096 + R * 256 + ((kg * 16) ^ ((R & 7) << 4))) = cv.v;
    }
    if (tid < 512) {
        const int idx = tid & 127, seg = tid >> 7;
        float v;
        if      (seg == 0) v = b1[o * HID + idx];
        else if (seg == 1) v = bh[o * HID + idx];
        else if (seg == 2) v = bh[(OUT_DIM + o) * HID + idx];
        else               v = Wo[o * HID + idx];
        sBias[tid] = v;
    }
    __syncthreads();   // the ONLY block-wide barrier

    const int lane = tid & 63;
    const int w    = tid >> 6;
    const int n    = lane & 15;
    const int q    = lane >> 4;
    const float bo_v = bo[o];

    int kW1[2], kWh[4];
    #pragma unroll
    for (int kc = 0; kc < 2; ++kc) kW1[kc] = ((4 * kc + q) ^ (n & 7)) << 4;
    #pragma unroll
    for (int kc = 0; kc < 4; ++kc) kWh[kc] = ((4 * kc + q) ^ (n & 7)) << 4;

    const int w1base = n * 128;
    const int whbase = n * 256;
    const int bbase  = 32 * q;

    for (int it = 0; it < n_iters; ++it) {
        unsigned z = 0;
        asm volatile("" : "+v"(z));        // anti-LICM launder (R4 lesson)
        const char* const W1p = cW1 + w1base + z;
        const char* const Whp = cWh + whbase + z;
        const char* const Bp  = cB  + bbase  + z;

        const int row = (slice * n_iters + it) * 256 + w * 16 + n;

        v8s xb[2];
        if constexpr (BF16X) {
            const char* xr = (const char*)(xbf + (size_t)row * IN_DIM) + q * 16;
            xb[0] = *(const v8s*)(xr);
            xb[1] = *(const v8s*)(xr + 64);
        } else {
            #pragma unroll
            for (int kc = 0; kc < 2; ++kc) {
                const float* xp = x + (size_t)row * IN_DIM + kc * 32 + q * 8;
                float4 f0 = *(const float4*)xp;
                float4 f1 = *(const float4*)(xp + 4);
                union { v8s v; unsigned u[4]; } cv;
                cv.u[0] = pk2(f0.x, f0.y); cv.u[1] = pk2(f0.z, f0.w);
                cv.u[2] = pk2(f1.x, f1.y); cv.u[3] = pk2(f1.z, f1.w);
                xb[kc] = cv.v;
            }
        }

        // ---------------- layer 1 ----------------
        v4f acc[8];
        #pragma unroll
        for (int T = 0; T < 8; ++T)
            acc[T] = *(const v4f*)(Bp + 128 * (T >> 1) + 16 * (T & 1));
        #pragma unroll
        for (int kc = 0; kc < 2; ++kc)
            #pragma unroll
            for (int T = 0; T < 8; ++T) {
                v8s a = *(const v8s*)(W1p + T * 2048 + kW1[kc]);
                acc[T] = __builtin_amdgcn_mfma_f32_16x16x32_bf16(a, xb[kc], acc[T], 0, 0, 0);
            }
        unsigned h[16];
        #pragma unroll
        for (int T = 0; T < 8; ++T) {
            v4f s = POLY ? swish_p4(acc[T], SP) : swish4(acc[T]);
            const int i0 = (T >> 1) * 4 + 2 * (T & 1);
            h[i0]     = pk2(s[0], s[1]);
            h[i0 + 1] = pk2(s[2], s[3]);
        }

        // ---------------- hidden layers ----------------
        #pragma unroll
        for (int l = 0; l < 2; ++l) {
            #pragma unroll
            for (int T = 0; T < 8; ++T)
                acc[T] = *(const v4f*)(Bp + 512 + l * 512 + 128 * (T >> 1) + 16 * (T & 1));
            #pragma unroll
            for (int kc = 0; kc < 4; ++kc) {
                v4u tu = { h[kc * 4 + 0], h[kc * 4 + 1], h[kc * 4 + 2], h[kc * 4 + 3] };
                v8s hbv = __builtin_bit_cast(v8s, tu);
                #pragma unroll
                for (int T = 0; T < 8; ++T) {
                    v8s a = *(const v8s*)(Whp + l * 32768 + T * 4096 + kWh[kc]);
                    acc[T] = __builtin_amdgcn_mfma_f32_16x16x32_bf16(a, hbv, acc[T], 0, 0, 0);
                }
            }
            if (l == 0) {
                #pragma unroll
                for (int T = 0; T < 8; ++T) {
                    v4f s = POLY ? swish_p4(acc[T], SP) : swish4(acc[T]);
                    const int i0 = (T >> 1) * 4 + 2 * (T & 1);
                    h[i0]     = pk2(s[0], s[1]);
                    h[i0 + 1] = pk2(s[2], s[3]);
                }
            } else {
                float p = 0.0f;
                #pragma unroll
                for (int T = 0; T < 8; ++T) {
                    v4f wo = *(const v4f*)(Bp + 1536 + 128 * (T >> 1) + 16 * (T & 1));
                    v4f s  = POLY ? swish_p4(acc[T], SP) : swish4(acc[T]);
                    p += s[0] * wo[0];
                    p += s[1] * wo[1];
                    p += s[2] * wo[2];
                    p += s[3] * wo[3];
                }
                p += __shfl_xor(p, 16);
                p += __shfl_xor(p, 32);
                if (lane < 16)
                    out[(size_t)row * OUT_DIM + o] = p + bo_v;
            }
        }
    }
}

// ---------------- host: fit sigmoid poly once, verify in float ----------------
struct SigFit { SigP p; bool ok; };

static SigFit make_fit() {
    SigFit F{}; F.ok = false;
    constexpr int NC = SIG_NC;
    const double CL = (double)SIG_CL, zmax = CL * CL;
    const int NS = 6000;
    double A[NC][NC] = {}, rhs[NC] = {};
    for (int i = 0; i < NS; ++i) {
        double v = CL * (i + 0.5) / NS;
        double zz = v * v, s = 2.0 * zz / zmax - 1.0;
        double g = (1.0 / (1.0 + std::exp(-v)) - 0.5) / v;
        double T[NC]; T[0] = 1; T[1] = s;
        for (int k = 2; k < NC; ++k) T[k] = 2 * s * T[k - 1] - T[k - 2];
        double wt = 0.05 + zz; wt = wt * wt;   // ~z^2: swish err = z * g_err
        for (int r = 0; r < NC; ++r) {
            rhs[r] += wt * T[r] * g;
            for (int c = 0; c < NC; ++c) A[r][c] += wt * T[r] * T[c];
        }
    }
    double a[NC];
    {   // Gaussian elimination, partial pivot
        double M[NC][NC + 1];
        for (int r = 0; r < NC; ++r) { for (int c = 0; c < NC; ++c) M[r][c] = A[r][c]; M[r][NC] = rhs[r]; }
        for (int col = 0; col < NC; ++col) {
            int piv = col;
            for (int r = col + 1; r < NC; ++r)
                if (std::fabs(M[r][col]) > std::fabs(M[piv][col])) piv = r;
            for (int c = col; c <= NC; ++c) std::swap(M[piv][c], M[col][c]);
            if (std::fabs(M[col][col]) < 1e-280) return F;
            for (int r = col + 1; r < NC; ++r) {
                double f = M[r][col] / M[col][col];
                for (int c = col; c <= NC; ++c) M[r][c] -= f * M[col][c];
            }
        }
        for (int r = NC - 1; r >= 0; --r) {
            double acc2 = M[r][NC];
            for (int c = r + 1; c < NC; ++c) acc2 -= M[r][c] * a[c];
            a[r] = acc2 / M[r][r];
        }
    }
    // Chebyshev -> monomial in s
    double mono[NC] = {}, tp[NC] = {}, tc[NC] = {}, tn[NC];
    tp[0] = 1;
    for (int j = 0; j < NC; ++j) mono[j] += a[0] * tp[j];
    tc[1] = 1;
    for (int j = 0; j < NC; ++j) mono[j] += a[1] * tc[j];
    for (int k = 2; k < NC; ++k) {
        tn[0] = -tp[0];
        for (int j = 1; j < NC; ++j) tn[j] = 2 * tc[j - 1] - tp[j];
        for (int j = 0; j < NC; ++j) mono[j] += a[k] * tn[j];
        for (int j = 0; j < NC; ++j) { tp[j] = tc[j]; tc[j] = tn[j]; }
    }
    F.p.k1 = (float)(2.0 / zmax);
    for (int j = 0; j < NC; ++j) F.p.c[j] = (float)mono[j];
    // float verification with kernel-identical arithmetic, over [-12, 12]
    double maxerr = 0;
    for (int i = 0; i <= 6000; ++i) {
        float v = -12.f + 24.f * (float)i / 6000.f;
        float u = fminf(fmaxf(v, -SIG_CL), SIG_CL);
        float zz = u * u;
        float s = fmaf(zz, F.p.k1, -1.0f);
        float g = F.p.c[NC - 1];
        for (int k = NC - 2; k >= 0; --k) g = fmaf(g, s, F.p.c[k]);
        float sig = fmaf(u, g, 0.5f);
        float sw = v * sig;
        double swt = (double)v / (1.0 + std::exp(-(double)v));
        maxerr = std::max(maxerr, std::fabs((double)sw - swt));
    }
    F.ok = (maxerr < 1.5e-3);
    return F;
}

extern "C" void kernel_launch(void* const* d_in, const int* in_sizes, int n_in,
                              void* d_out, int out_size, void* d_ws, size_t ws_size,
                              hipStream_t stream) {
    const float* x  = (const float*)d_in[0];
    const float* W1 = (const float*)d_in[1];
    const float* b1 = (const float*)d_in[2];
    const float* Wh = (const float*)d_in[3];
    const float* bh = (const float*)d_in[4];
    const float* Wo = (const float*)d_in[5];
    const float* bo = (const float*)d_in[6];
    float* out = (float*)d_out;

    const int N       = in_sizes[0] / IN_DIM;  // 32768
    const int n_iters = N / (8 * 256);         // 16

    dim3 grid(OUT_DIM * 8);                    // 256 blocks = 1/CU
    dim3 block(1024);

    static const SigFit SF = make_fit();       // host fit, once

    const size_t need = (size_t)N * IN_DIM * sizeof(ushort);   // 4 MB
    const bool bf = (d_ws != nullptr && ws_size >= need);
    if (bf) {
        ushort* xbf = (ushort*)d_ws;
        const int n8 = N * IN_DIM / 8;
        cvt_x<<<dim3((n8 + 1023) / 1024), dim3(1024), 0, stream>>>(x, xbf, n8);
        if (SF.ok) subnet_mlp<1, 1><<<grid, block, 0, stream>>>(x, xbf, W1, b1, Wh, bh, Wo, bo, out, n_iters, SF.p);
        else       subnet_mlp<1, 0><<<grid, block, 0, stream>>>(x, xbf, W1, b1, Wh, bh, Wo, bo, out, n_iters, SF.p);
    } else {
        if (SF.ok) subnet_mlp<0, 1><<<grid, block, 0, stream>>>(x, nullptr, W1, b1, Wh, bh, Wo, bo, out, n_iters, SF.p);
        else       subnet_mlp<0, 0><<<grid, block, 0, stream>>>(x, nullptr, W1, b1, Wh, bh, Wo, bo, out, n_iters, SF.p);
    }
}

// Round 13
// 225.646 us; speedup vs baseline: 1.3309x; 1.3309x over previous
//
#include <hip/hip_runtime.h>
#include <hip/hip_bf16.h>

#define IN_DIM  64
#define HID     128
#define OUT_DIM 32

typedef short    v8s __attribute__((ext_vector_type(8)));
typedef float    v4f __attribute__((ext_vector_type(4)));
typedef unsigned v4u __attribute__((ext_vector_type(4)));

__device__ __forceinline__ unsigned pk2(float a, float b) {
    __hip_bfloat162 p = __float22bfloat162_rn(make_float2(a, b));
    return *(unsigned*)&p;
}
// single-instruction HW pack (RNE), T12 technique: lo->bits[15:0], hi->bits[31:16]
__device__ __forceinline__ unsigned pk2hw(float lo, float hi) {
    unsigned r;
    asm("v_cvt_pk_bf16_f32 %0, %1, %2" : "=v"(r) : "v"(lo), "v"(hi));
    return r;
}

// grouped-reciprocal swish: 4 swish with ONE v_rcp (measured best, R10=183us)
__device__ __forceinline__ v4f swish4(v4f v) {
    float e0 = __expf(fminf(-v[0], 20.0f));
    float e1 = __expf(fminf(-v[1], 20.0f));
    float e2 = __expf(fminf(-v[2], 20.0f));
    float e3 = __expf(fminf(-v[3], 20.0f));
    float w0 = 1.0f + e0, w1 = 1.0f + e1, w2 = 1.0f + e2, w3 = 1.0f + e3;
    float w01 = w0 * w1, w23 = w2 * w3;
    float r   = __builtin_amdgcn_rcpf(w01 * w23);
    float r01 = r * w23, r23 = r * w01;
    v4f s;
    s[0] = v[0] * (w1 * r01);
    s[1] = v[1] * (w0 * r01);
    s[2] = v[2] * (w3 * r23);
    s[3] = v[3] * (w2 * r23);
    return s;
}

// one-time x fp32 -> bf16 (row-major [N][64])
__global__ __launch_bounds__(1024)
void cvt_x(const float* __restrict__ x, ushort* __restrict__ xb, int n8) {
    int i = blockIdx.x * blockDim.x + threadIdx.x;
    if (i < n8) {
        float4 f0 = *(const float4*)(x + (size_t)i * 8);
        float4 f1 = *(const float4*)(x + (size_t)i * 8 + 4);
        uint4 u;
        u.x = pk2(f0.x, f0.y); u.y = pk2(f0.z, f0.w);
        u.z = pk2(f1.x, f1.y); u.w = pk2(f1.z, f1.w);
        *(uint4*)(xb + (size_t)i * 8) = u;
    }
}

// Channel-permuted weight staging: tile T, row R holds physical channel
//   ch(T,R) = 32*(T>>1) + 8*(R>>2) + 4*(T&1) + (R&3)
// -> each layer's MFMA C-output registers ARE the next layer's B-operand
// fragments (register-local handoff, zero main-loop barriers/slab).
// R10 base (183us): bias in LDS, bf16-x workspace, opaque-z anti-LICM launder.
// R13 edits: (1) hot-path packs use v_cvt_pk_bf16_f32 (1 op vs ~9-op SW RNE);
//            (2) next-iter x fragments prefetched right after L1's MFMAs.
template<int BF16X>
__global__ __launch_bounds__(1024, 1)
void subnet_mlp(const float* __restrict__ x,  const ushort* __restrict__ xbf,
                const float* __restrict__ W1, const float* __restrict__ b1,
                const float* __restrict__ Wh, const float* __restrict__ bh,
                const float* __restrict__ Wo, const float* __restrict__ bo,
                float* __restrict__ out, int n_iters)
{
    __shared__ __align__(16) short sW1[8 * 16 * 64];       // 16 KB
    __shared__ __align__(16) short sWh[2 * 8 * 16 * 128];  // 64 KB
    __shared__ __align__(16) float sBias[512];             // 2 KB

    const int tid   = threadIdx.x;
    const int o     = blockIdx.x >> 3;
    const int slice = blockIdx.x & 7;

    char* const cW1 = (char*)sW1;
    char* const cWh = (char*)sWh;
    char* const cB  = (char*)sBias;

    {   // W1 staging: 1024 tasks (T,R,kg)
        const int R = tid & 15, T = (tid >> 4) & 7, kg = tid >> 7;
        const int c = 32 * (T >> 1) + 8 * (R >> 2) + 4 * (T & 1) + (R & 3);
        const float* p = W1 + ((size_t)o * IN_DIM + kg * 8) * HID + c;
        union { v8s v; unsigned u[4]; } cv;
        #pragma unroll
        for (int j = 0; j < 4; ++j)
            cv.u[j] = pk2(p[(2 * j) * HID], p[(2 * j + 1) * HID]);
        *(v8s*)(cW1 + T * 2048 + R * 128 + ((kg * 16) ^ ((R & 7) << 4))) = cv.v;
    }
    #pragma unroll
    for (int r = 0; r < 4; ++r) {   // Wh staging: 4096 tasks
        const int t = tid + r * 1024;
        const int R = t & 15, T = (t >> 4) & 7, kg = (t >> 7) & 15, l = t >> 11;
        const int c = 32 * (T >> 1) + 8 * (R >> 2) + 4 * (T & 1) + (R & 3);
        const float* p = Wh + (((size_t)l * OUT_DIM + o) * HID + kg * 8) * HID + c;
        union { v8s v; unsigned u[4]; } cv;
        #pragma unroll
        for (int j = 0; j < 4; ++j)
            cv.u[j] = pk2(p[(2 * j) * HID], p[(2 * j + 1) * HID]);
        *(v8s*)(cWh + l * 32768 + T * 4096 + R * 256 + ((kg * 16) ^ ((R & 7) << 4))) = cv.v;
    }
    if (tid < 512) {
        const int idx = tid & 127, seg = tid >> 7;
        float v;
        if      (seg == 0) v = b1[o * HID + idx];
        else if (seg == 1) v = bh[o * HID + idx];
        else if (seg == 2) v = bh[(OUT_DIM + o) * HID + idx];
        else               v = Wo[o * HID + idx];
        sBias[tid] = v;
    }
    __syncthreads();   // the ONLY block-wide barrier

    const int lane = tid & 63;
    const int w    = tid >> 6;
    const int n    = lane & 15;
    const int q    = lane >> 4;
    const float bo_v = bo[o];

    int kW1[2], kWh[4];
    #pragma unroll
    for (int kc = 0; kc < 2; ++kc) kW1[kc] = ((4 * kc + q) ^ (n & 7)) << 4;
    #pragma unroll
    for (int kc = 0; kc < 4; ++kc) kWh[kc] = ((4 * kc + q) ^ (n & 7)) << 4;

    const int w1base = n * 128;
    const int whbase = n * 256;
    const int bbase  = 32 * q;

    // ---- x fragment prefetch state (rotated each iteration) ----
    v8s xa0, xa1;
    if constexpr (BF16X) {
        const int row0 = (slice * n_iters + 0) * 256 + w * 16 + n;
        const char* xr = (const char*)(xbf + (size_t)row0 * IN_DIM) + q * 16;
        xa0 = *(const v8s*)(xr);
        xa1 = *(const v8s*)(xr + 64);
    }

    for (int it = 0; it < n_iters; ++it) {
        unsigned z = 0;
        asm volatile("" : "+v"(z));        // anti-LICM launder (R4 lesson)
        const char* const W1p = cW1 + w1base + z;
        const char* const Whp = cWh + whbase + z;
        const char* const Bp  = cB  + bbase  + z;

        const int row = (slice * n_iters + it) * 256 + w * 16 + n;

        v8s xb[2];
        if constexpr (BF16X) {
            xb[0] = xa0;
            xb[1] = xa1;
        } else {
            #pragma unroll
            for (int kc = 0; kc < 2; ++kc) {
                const float* xp = x + (size_t)row * IN_DIM + kc * 32 + q * 8;
                float4 f0 = *(const float4*)xp;
                float4 f1 = *(const float4*)(xp + 4);
                union { v8s v; unsigned u[4]; } cv;
                cv.u[0] = pk2(f0.x, f0.y); cv.u[1] = pk2(f0.z, f0.w);
                cv.u[2] = pk2(f1.x, f1.y); cv.u[3] = pk2(f1.z, f1.w);
                xb[kc] = cv.v;
            }
        }

        // ---------------- layer 1 ----------------
        v4f acc[8];
        #pragma unroll
        for (int T = 0; T < 8; ++T)
            acc[T] = *(const v4f*)(Bp + 128 * (T >> 1) + 16 * (T & 1));
        #pragma unroll
        for (int kc = 0; kc < 2; ++kc)
            #pragma unroll
            for (int T = 0; T < 8; ++T) {
                v8s a = *(const v8s*)(W1p + T * 2048 + kW1[kc]);
                acc[T] = __builtin_amdgcn_mfma_f32_16x16x32_bf16(a, xb[kc], acc[T], 0, 0, 0);
            }

        // prefetch next iteration's x fragments (full-iteration load-to-use gap)
        if constexpr (BF16X) {
            const int itn  = (it + 1 < n_iters) ? it + 1 : it;
            const int rown = (slice * n_iters + itn) * 256 + w * 16 + n;
            const char* xrn = (const char*)(xbf + (size_t)rown * IN_DIM) + q * 16;
            xa0 = *(const v8s*)(xrn);
            xa1 = *(const v8s*)(xrn + 64);
        }

        unsigned h[16];
        #pragma unroll
        for (int T = 0; T < 8; ++T) {
            v4f s = swish4(acc[T]);
            const int i0 = (T >> 1) * 4 + 2 * (T & 1);
            h[i0]     = pk2hw(s[0], s[1]);
            h[i0 + 1] = pk2hw(s[2], s[3]);
        }

        // ---------------- hidden layers ----------------
        #pragma unroll
        for (int l = 0; l < 2; ++l) {
            #pragma unroll
            for (int T = 0; T < 8; ++T)
                acc[T] = *(const v4f*)(Bp + 512 + l * 512 + 128 * (T >> 1) + 16 * (T & 1));
            #pragma unroll
            for (int kc = 0; kc < 4; ++kc) {
                v4u tu = { h[kc * 4 + 0], h[kc * 4 + 1], h[kc * 4 + 2], h[kc * 4 + 3] };
                v8s hbv = __builtin_bit_cast(v8s, tu);
                #pragma unroll
                for (int T = 0; T < 8; ++T) {
                    v8s a = *(const v8s*)(Whp + l * 32768 + T * 4096 + kWh[kc]);
                    acc[T] = __builtin_amdgcn_mfma_f32_16x16x32_bf16(a, hbv, acc[T], 0, 0, 0);
                }
            }
            if (l == 0) {
                #pragma unroll
                for (int T = 0; T < 8; ++T) {
                    v4f s = swish4(acc[T]);
                    const int i0 = (T >> 1) * 4 + 2 * (T & 1);
                    h[i0]     = pk2hw(s[0], s[1]);
                    h[i0 + 1] = pk2hw(s[2], s[3]);
                }
            } else {
                float p = 0.0f;
                #pragma unroll
                for (int T = 0; T < 8; ++T) {
                    v4f wo = *(const v4f*)(Bp + 1536 + 128 * (T >> 1) + 16 * (T & 1));
                    v4f s  = swish4(acc[T]);
                    p += s[0] * wo[0];
                    p += s[1] * wo[1];
                    p += s[2] * wo[2];
                    p += s[3] * wo[3];
                }
                p += __shfl_xor(p, 16);
                p += __shfl_xor(p, 32);
                if (lane < 16)
                    out[(size_t)row * OUT_DIM + o] = p + bo_v;
            }
        }
    }
}

extern "C" void kernel_launch(void* const* d_in, const int* in_sizes, int n_in,
                              void* d_out, int out_size, void* d_ws, size_t ws_size,
                              hipStream_t stream) {
    const float* x  = (const float*)d_in[0];
    const float* W1 = (const float*)d_in[1];
    const float* b1 = (const float*)d_in[2];
    const float* Wh = (const float*)d_in[3];
    const float* bh = (const float*)d_in[4];
    const float* Wo = (const float*)d_in[5];
    const float* bo = (const float*)d_in[6];
    float* out = (float*)d_out;

    const int N       = in_sizes[0] / IN_DIM;  // 32768
    const int n_iters = N / (8 * 256);         // 16

    dim3 grid(OUT_DIM * 8);                    // 256 blocks = 1/CU
    dim3 block(1024);

    const size_t need = (size_t)N * IN_DIM * sizeof(ushort);   // 4 MB
    if (d_ws != nullptr && ws_size >= need) {
        ushort* xbf = (ushort*)d_ws;
        const int n8 = N * IN_DIM / 8;
        cvt_x<<<dim3((n8 + 1023) / 1024), dim3(1024), 0, stream>>>(x, xbf, n8);
        subnet_mlp<1><<<grid, block, 0, stream>>>(x, xbf, W1, b1, Wh, bh, Wo, bo, out, n_iters);
    } else {
        subnet_mlp<0><<<grid, block, 0, stream>>>(x, nullptr, W1, b1, Wh, bh, Wo, bo, out, n_iters);
    }
}

// Round 14
// 215.735 us; speedup vs baseline: 1.3921x; 1.0459x over previous
//
#include <hip/hip_runtime.h>
#include <hip/hip_bf16.h>

#define IN_DIM  64
#define HID     128
#define OUT_DIM 32
#define LOG2E_F 1.4426950408889634f
#define LN2_F   0.6931471805599453f

typedef short    v8s __attribute__((ext_vector_type(8)));
typedef float    v4f __attribute__((ext_vector_type(4)));
typedef unsigned v4u __attribute__((ext_vector_type(4)));

__device__ __forceinline__ unsigned pk2(float a, float b) {
    __hip_bfloat162 p = __float22bfloat162_rn(make_float2(a, b));
    return *(unsigned*)&p;
}
// single-instruction HW pack (RNE): lo->bits[15:0], hi->bits[31:16]
__device__ __forceinline__ unsigned pk2hw(float lo, float hi) {
    unsigned r;
    asm("v_cvt_pk_bf16_f32 %0, %1, %2" : "=v"(r) : "v"(lo), "v"(hi));
    return r;
}
// raw v_exp_f32 (2^x), no libm wrapper/fixup
__device__ __forceinline__ float exp2raw(float x) {
    float r;
    asm("v_exp_f32 %0, %1" : "=v"(r) : "v"(x));
    return r;
}

// Scaled-domain grouped-reciprocal swish.
// Input v' = v_true * log2e (weights/x/bias pre-scaled). sigma = 1/(1+2^(-v')).
// Returns s_i = v'_i * sigma_i = swish(v_true) * log2e -- which is EXACTLY the
// next layer's required input scale (ln2*log2e cancels), so hidden handoff
// needs no correction; only wo is pre-scaled by ln2 at staging.
// Clamp at 28: group product <= (2^28+1)^4 ~ 1.1e34 < FLT_MAX; for v'< -28
// sigma ~ 2^-28 -> s ~ 0 (true swish there is ~1e-7).
__device__ __forceinline__ v4f swish4x(v4f v) {
    float m0 = fminf(-v[0], 28.0f);
    float m1 = fminf(-v[1], 28.0f);
    float m2 = fminf(-v[2], 28.0f);
    float m3 = fminf(-v[3], 28.0f);
    float e0 = exp2raw(m0), e1 = exp2raw(m1), e2 = exp2raw(m2), e3 = exp2raw(m3);
    float w0 = 1.0f + e0, w1 = 1.0f + e1, w2 = 1.0f + e2, w3 = 1.0f + e3;
    float w01 = w0 * w1, w23 = w2 * w3;
    float r   = __builtin_amdgcn_rcpf(w01 * w23);
    float r01 = r * w23, r23 = r * w01;          // 1/w01, 1/w23
    v4f s;
    s[0] = v[0] * (w1 * r01);
    s[1] = v[1] * (w0 * r01);
    s[2] = v[2] * (w3 * r23);
    s[3] = v[3] * (w2 * r23);
    return s;
}

// one-time x fp32 -> bf16(x * log2e)  (row-major [N][64])
__global__ __launch_bounds__(1024)
void cvt_x(const float* __restrict__ x, ushort* __restrict__ xb, int n8) {
    int i = blockIdx.x * blockDim.x + threadIdx.x;
    if (i < n8) {
        float4 f0 = *(const float4*)(x + (size_t)i * 8);
        float4 f1 = *(const float4*)(x + (size_t)i * 8 + 4);
        uint4 u;
        u.x = pk2(f0.x * LOG2E_F, f0.y * LOG2E_F);
        u.y = pk2(f0.z * LOG2E_F, f0.w * LOG2E_F);
        u.z = pk2(f1.x * LOG2E_F, f1.y * LOG2E_F);
        u.w = pk2(f1.z * LOG2E_F, f1.w * LOG2E_F);
        *(uint4*)(xb + (size_t)i * 8) = u;
    }
}

// Channel-permuted weight staging: tile T, row R holds physical channel
//   ch(T,R) = 32*(T>>1) + 8*(R>>2) + 4*(T&1) + (R&3)
// -> each layer's MFMA C-output registers ARE the next layer's B-operand
// fragments (register-local handoff, zero main-loop barriers/slab).
// R13 base (176us). R14: exp2-scaled domain -- x,b *log2e; wo *ln2; raw v_exp.
template<int BF16X>
__global__ __launch_bounds__(1024, 1)
void subnet_mlp(const float* __restrict__ x,  const ushort* __restrict__ xbf,
                const float* __restrict__ W1, const float* __restrict__ b1,
                const float* __restrict__ Wh, const float* __restrict__ bh,
                const float* __restrict__ Wo, const float* __restrict__ bo,
                float* __restrict__ out, int n_iters)
{
    __shared__ __align__(16) short sW1[8 * 16 * 64];       // 16 KB
    __shared__ __align__(16) short sWh[2 * 8 * 16 * 128];  // 64 KB
    __shared__ __align__(16) float sBias[512];             // 2 KB (scaled)

    const int tid   = threadIdx.x;
    const int o     = blockIdx.x >> 3;
    const int slice = blockIdx.x & 7;

    char* const cW1 = (char*)sW1;
    char* const cWh = (char*)sWh;
    char* const cB  = (char*)sBias;

    {   // W1 staging: 1024 tasks (T,R,kg)  (weights UNscaled)
        const int R = tid & 15, T = (tid >> 4) & 7, kg = tid >> 7;
        const int c = 32 * (T >> 1) + 8 * (R >> 2) + 4 * (T & 1) + (R & 3);
        const float* p = W1 + ((size_t)o * IN_DIM + kg * 8) * HID + c;
        union { v8s v; unsigned u[4]; } cv;
        #pragma unroll
        for (int j = 0; j < 4; ++j)
            cv.u[j] = pk2(p[(2 * j) * HID], p[(2 * j + 1) * HID]);
        *(v8s*)(cW1 + T * 2048 + R * 128 + ((kg * 16) ^ ((R & 7) << 4))) = cv.v;
    }
    #pragma unroll
    for (int r = 0; r < 4; ++r) {   // Wh staging: 4096 tasks
        const int t = tid + r * 1024;
        const int R = t & 15, T = (t >> 4) & 7, kg = (t >> 7) & 15, l = t >> 11;
        const int c = 32 * (T >> 1) + 8 * (R >> 2) + 4 * (T & 1) + (R & 3);
        const float* p = Wh + (((size_t)l * OUT_DIM + o) * HID + kg * 8) * HID + c;
        union { v8s v; unsigned u[4]; } cv;
        #pragma unroll
        for (int j = 0; j < 4; ++j)
            cv.u[j] = pk2(p[(2 * j) * HID], p[(2 * j + 1) * HID]);
        *(v8s*)(cWh + l * 32768 + T * 4096 + R * 256 + ((kg * 16) ^ ((R & 7) << 4))) = cv.v;
    }
    if (tid < 512) {   // biases *log2e (exp2 domain); head weights *ln2 (undo)
        const int idx = tid & 127, seg = tid >> 7;
        float v;
        if      (seg == 0) v = b1[o * HID + idx] * LOG2E_F;
        else if (seg == 1) v = bh[o * HID + idx] * LOG2E_F;
        else if (seg == 2) v = bh[(OUT_DIM + o) * HID + idx] * LOG2E_F;
        else               v = Wo[o * HID + idx] * LN2_F;
        sBias[tid] = v;
    }
    __syncthreads();   // the ONLY block-wide barrier

    const int lane = tid & 63;
    const int w    = tid >> 6;
    const int n    = lane & 15;
    const int q    = lane >> 4;
    const float bo_v = bo[o];

    int kW1[2], kWh[4];
    #pragma unroll
    for (int kc = 0; kc < 2; ++kc) kW1[kc] = ((4 * kc + q) ^ (n & 7)) << 4;
    #pragma unroll
    for (int kc = 0; kc < 4; ++kc) kWh[kc] = ((4 * kc + q) ^ (n & 7)) << 4;

    const int w1base = n * 128;
    const int whbase = n * 256;
    const int bbase  = 32 * q;

    // ---- x fragment prefetch state (rotated each iteration) ----
    v8s xa0, xa1;
    if constexpr (BF16X) {
        const int row0 = (slice * n_iters + 0) * 256 + w * 16 + n;
        const char* xr = (const char*)(xbf + (size_t)row0 * IN_DIM) + q * 16;
        xa0 = *(const v8s*)(xr);
        xa1 = *(const v8s*)(xr + 64);
    }

    for (int it = 0; it < n_iters; ++it) {
        unsigned z = 0;
        asm volatile("" : "+v"(z));        // anti-LICM launder (R4 lesson)
        const char* const W1p = cW1 + w1base + z;
        const char* const Whp = cWh + whbase + z;
        const char* const Bp  = cB  + bbase  + z;

        const int row = (slice * n_iters + it) * 256 + w * 16 + n;

        v8s xb[2];
        if constexpr (BF16X) {
            xb[0] = xa0;
            xb[1] = xa1;
        } else {
            #pragma unroll
            for (int kc = 0; kc < 2; ++kc) {   // fallback: scale by log2e here
                const float* xp = x + (size_t)row * IN_DIM + kc * 32 + q * 8;
                float4 f0 = *(const float4*)xp;
                float4 f1 = *(const float4*)(xp + 4);
                union { v8s v; unsigned u[4]; } cv;
                cv.u[0] = pk2(f0.x * LOG2E_F, f0.y * LOG2E_F);
                cv.u[1] = pk2(f0.z * LOG2E_F, f0.w * LOG2E_F);
                cv.u[2] = pk2(f1.x * LOG2E_F, f1.y * LOG2E_F);
                cv.u[3] = pk2(f1.z * LOG2E_F, f1.w * LOG2E_F);
                xb[kc] = cv.v;
            }
        }

        // ---------------- layer 1 ----------------
        v4f acc[8];
        #pragma unroll
        for (int T = 0; T < 8; ++T)
            acc[T] = *(const v4f*)(Bp + 128 * (T >> 1) + 16 * (T & 1));
        #pragma unroll
        for (int kc = 0; kc < 2; ++kc)
            #pragma unroll
            for (int T = 0; T < 8; ++T) {
                v8s a = *(const v8s*)(W1p + T * 2048 + kW1[kc]);
                acc[T] = __builtin_amdgcn_mfma_f32_16x16x32_bf16(a, xb[kc], acc[T], 0, 0, 0);
            }

        // prefetch next iteration's x fragments (full-iteration load-to-use gap)
        if constexpr (BF16X) {
            const int itn  = (it + 1 < n_iters) ? it + 1 : it;
            const int rown = (slice * n_iters + itn) * 256 + w * 16 + n;
            const char* xrn = (const char*)(xbf + (size_t)rown * IN_DIM) + q * 16;
            xa0 = *(const v8s*)(xrn);
            xa1 = *(const v8s*)(xrn + 64);
        }

        unsigned h[16];
        #pragma unroll
        for (int T = 0; T < 8; ++T) {
            v4f s = swish4x(acc[T]);       // s = swish*log2e = next-layer input
            const int i0 = (T >> 1) * 4 + 2 * (T & 1);
            h[i0]     = pk2hw(s[0], s[1]);
            h[i0 + 1] = pk2hw(s[2], s[3]);
        }

        // ---------------- hidden layers ----------------
        #pragma unroll
        for (int l = 0; l < 2; ++l) {
            #pragma unroll
            for (int T = 0; T < 8; ++T)
                acc[T] = *(const v4f*)(Bp + 512 + l * 512 + 128 * (T >> 1) + 16 * (T & 1));
            #pragma unroll
            for (int kc = 0; kc < 4; ++kc) {
                v4u tu = { h[kc * 4 + 0], h[kc * 4 + 1], h[kc * 4 + 2], h[kc * 4 + 3] };
                v8s hbv = __builtin_bit_cast(v8s, tu);
                #pragma unroll
                for (int T = 0; T < 8; ++T) {
                    v8s a = *(const v8s*)(Whp + l * 32768 + T * 4096 + kWh[kc]);
                    acc[T] = __builtin_amdgcn_mfma_f32_16x16x32_bf16(a, hbv, acc[T], 0, 0, 0);
                }
            }
            if (l == 0) {
                #pragma unroll
                for (int T = 0; T < 8; ++T) {
                    v4f s = swish4x(acc[T]);
                    const int i0 = (T >> 1) * 4 + 2 * (T & 1);
                    h[i0]     = pk2hw(s[0], s[1]);
                    h[i0 + 1] = pk2hw(s[2], s[3]);
                }
            } else {
                // head: s = swish*log2e, wo pre-scaled by ln2 -> exact
                float p = 0.0f;
                #pragma unroll
                for (int T = 0; T < 8; ++T) {
                    v4f wo = *(const v4f*)(Bp + 1536 + 128 * (T >> 1) + 16 * (T & 1));
                    v4f s  = swish4x(acc[T]);
                    p += s[0] * wo[0];
                    p += s[1] * wo[1];
                    p += s[2] * wo[2];
                    p += s[3] * wo[3];
                }
                p += __shfl_xor(p, 16);
                p += __shfl_xor(p, 32);
                if (lane < 16)
                    out[(size_t)row * OUT_DIM + o] = p + bo_v;
            }
        }
    }
}

extern "C" void kernel_launch(void* const* d_in, const int* in_sizes, int n_in,
                              void* d_out, int out_size, void* d_ws, size_t ws_size,
                              hipStream_t stream) {
    const float* x  = (const float*)d_in[0];
    const float* W1 = (const float*)d_in[1];
    const float* b1 = (const float*)d_in[2];
    const float* Wh = (const float*)d_in[3];
    const float* bh = (const float*)d_in[4];
    const float* Wo = (const float*)d_in[5];
    const float* bo = (const float*)d_in[6];
    float* out = (float*)d_out;

    const int N       = in_sizes[0] / IN_DIM;  // 32768
    const int n_iters = N / (8 * 256);         // 16

    dim3 grid(OUT_DIM * 8);                    // 256 blocks = 1/CU
    dim3 block(1024);

    const size_t need = (size_t)N * IN_DIM * sizeof(ushort);   // 4 MB
    if (d_ws != nullptr && ws_size >= need) {
        ushort* xbf = (ushort*)d_ws;
        const int n8 = N * IN_DIM / 8;
        cvt_x<<<dim3((n8 + 1023) / 1024), dim3(1024), 0, stream>>>(x, xbf, n8);
        subnet_mlp<1><<<grid, block, 0, stream>>>(x, xbf, W1, b1, Wh, bh, Wo, bo, out, n_iters);
    } else {
        subnet_mlp<0><<<grid, block, 0, stream>>>(x, nullptr, W1, b1, Wh, bh, Wo, bo, out, n_iters);
    }
}